// Round 1
// baseline (518.215 us; speedup 1.0000x reference)
//
#include <hip/hip_runtime.h>

// Router_26817775796684 — MI355X/gfx950
// conv3x3(SAME)+relu+meanpool+fc+softmax+adaptive-threshold+sigmoid-renorm, fully fused.
//
// Structure:
//   kernel 1 (prep_weights): conv_w fp32 [co][ci][ky][kx] -> fp16 Bw[co][k], k = s*72+ci
//                            (ci padded 68->72, K padded 648->672 = 21 chunks of 32), in d_ws.
//   kernel 2 (router_main):  per WG = 4 samples. Patch staged once to LDS as fp16 [p][ci72]
//                            (144 B rows -> conflict-free). Conv = 9 shifted GEMMs via
//                            per-lane row-remap of the A fragment (16x16x32 f16 MFMA,
//                            verified layouts). B chunks (8 KB) streamed from L2 with
//                            register prefetch. Epilogue fused per wave/sample.

typedef _Float16 half8 __attribute__((ext_vector_type(8)));
typedef float    floatx4 __attribute__((ext_vector_type(4)));

#define LDS_A_SAMPLE 9216            // 64 rows * 144 B
#define LDS_B_OFF    36864           // 4 * LDS_A_SAMPLE
#define LDS_P_OFF    (36864 + 8192)  // pooled[4][128] fp32
#define LDS_TOTAL    (36864 + 8192 + 2048)

__global__ void prep_weights(const float* __restrict__ cw, _Float16* __restrict__ Bw) {
  int i = blockIdx.x * 256 + threadIdx.x;   // 0 .. 128*672-1
  int co = i / 672;
  int k  = i - co * 672;
  int s  = k / 72;                          // shift index (9 real, 9 = tail pad)
  int ci = k - s * 72;
  float v = 0.f;
  if (s < 9 && ci < 68) {
    int ky = s / 3, kx = s - 3 * ky;
    v = cw[((co * 68 + ci) * 3 + ky) * 3 + kx];
  }
  Bw[i] = (_Float16)v;                      // pads are EXACT zeros (never NaN)
}

__global__ __launch_bounds__(256, 2) void router_main(
    const float* __restrict__ patch,
    const float* __restrict__ conv_b,
    const _Float16* __restrict__ Bw,
    const float* __restrict__ fc_w,
    const float* __restrict__ fc_b,
    const float* __restrict__ p_wmax,
    const float* __restrict__ p_went,
    const float* __restrict__ p_wgap,
    const float* __restrict__ p_thr,
    const int* __restrict__ p_epoch,
    float* __restrict__ out)
{
  __shared__ __align__(16) unsigned char lds[LDS_TOTAL];
  const int tid    = threadIdx.x;
  const int l      = tid & 63;
  const int w      = tid >> 6;      // wave 0..3
  const int lane15 = l & 15;
  const int quad   = l >> 4;
  const int m_half = w >> 1;        // M 128-half
  const int n0     = (w & 1) * 64;  // N 64-half
  const int n_s    = blockIdx.x * 4;

  // ---- A staging: wave w stages sample (n_s+w); thread row p = l ----
  {
    const float* psrc = patch + (size_t)(n_s + w) * 4352 + l;     // [ci][p], p = l
    unsigned char* arow = lds + w * LDS_A_SAMPLE + l * 144;
    #pragma unroll
    for (int b = 0; b < 9; ++b) {                                 // ci blocks of 8 (72 cols)
      half8 h;
      #pragma unroll
      for (int j = 0; j < 8; ++j) {
        int ci = b * 8 + j;
        float v = (ci < 68) ? psrc[ci * 64] : 0.f;                // coalesced 256B per instr
        h[j] = (_Float16)v;
      }
      *(half8*)(arow + b * 16) = h;                               // ds_write_b128, uniform banks
    }
  }

  // ---- B chunk 0 -> LDS ([co][k32], unit u = co*4+quad at u*16) ----
  const int bco   = tid >> 1;
  const int bhalf = tid & 1;
  {
    const float4* src = (const float4*)(Bw + bco * 672 + bhalf * 16);
    float4 r0 = src[0], r1 = src[1];
    *(float4*)(lds + LDS_B_OFF + tid * 32)      = r0;
    *(float4*)(lds + LDS_B_OFF + tid * 32 + 16) = r1;
  }
  __syncthreads();

  // ---- K loop: 21 chunks of 32 over packed K = 672 ----
  floatx4 acc[8][4];
  floatx4 zacc = {0.f, 0.f, 0.f, 0.f};
  #pragma unroll
  for (int t = 0; t < 8; ++t)
    #pragma unroll
    for (int n = 0; n < 4; ++n) acc[t][n] = zacc;

  half8 zz;
  #pragma unroll
  for (int j = 0; j < 8; ++j) zz[j] = (_Float16)0.f;

  for (int c = 0; c < 21; ++c) {
    float4 pf0, pf1;
    if (c < 20) {                       // register prefetch of next B chunk (L2-hot)
      const float4* src = (const float4*)(Bw + bco * 672 + (c + 1) * 32 + bhalf * 16);
      pf0 = src[0]; pf1 = src[1];
    }
    // decode this lane's k block: kb = c*4+quad -> shift s, within-shift ci base
    int kb  = c * 4 + quad;             // 0..83
    int s   = (kb * 57) >> 9;           // kb/9  (exact for 0..83)
    int ci0 = (kb - s * 9) * 8;
    int dy  = (s * 11) >> 5;            // s/3
    int dx  = s - 3 * dy;
    bool kval = (kb < 81);              // kb 81..83 = zero tail pad

    half8 afr[8];
    #pragma unroll
    for (int t = 0; t < 8; ++t) {
      int p = (t & 3) * 16 + lane15;    // position within sample
      int y = p >> 3, x = p & 7;
      int sy = y + dy - 1, sx = x + dx - 1;
      bool v = kval && (sy >= 0) && (sy < 8) && (sx >= 0) && (sx < 8);
      int q = v ? (sy * 8 + sx) : 0;    // shifted source row (SAME padding -> zero frag)
      int g = m_half * 2 + (t >> 2);    // sample within WG
      afr[t] = *(const half8*)(lds + g * LDS_A_SAMPLE + q * 144 + ci0 * 2);
      afr[t] = v ? afr[t] : zz;
    }
    half8 bfr[4];
    #pragma unroll
    for (int n = 0; n < 4; ++n) {
      int co = n0 + n * 16 + lane15;
      bfr[n] = *(const half8*)(lds + LDS_B_OFF + co * 64 + quad * 16);
    }
    #pragma unroll
    for (int t = 0; t < 8; ++t)
      #pragma unroll
      for (int n = 0; n < 4; ++n)
        acc[t][n] = __builtin_amdgcn_mfma_f32_16x16x32_f16(afr[t], bfr[n], acc[t][n], 0, 0, 0);

    if (c < 20) {
      __syncthreads();                  // all waves done reading B chunk c
      *(float4*)(lds + LDS_B_OFF + tid * 32)      = pf0;
      *(float4*)(lds + LDS_B_OFF + tid * 32 + 16) = pf1;
      __syncthreads();                  // B chunk c+1 visible
    }
  }

  // ---- bias + relu + mean-pool (C layout: row = quad*4+reg, col = lane15) ----
  float bcoef[4];
  #pragma unroll
  for (int n = 0; n < 4; ++n) bcoef[n] = conv_b[n0 + n * 16 + lane15];

  float* pl = (float*)(lds + LDS_P_OFF);          // pooled[4][128]
  #pragma unroll
  for (int gl = 0; gl < 2; ++gl) {
    #pragma unroll
    for (int n = 0; n < 4; ++n) {
      float ssum = 0.f;
      #pragma unroll
      for (int tt = 0; tt < 4; ++tt) {
        int t = gl * 4 + tt;
        #pragma unroll
        for (int r = 0; r < 4; ++r)
          ssum += fmaxf(acc[t][n][r] + bcoef[n], 0.f);
      }
      ssum += __shfl_xor(ssum, 16);               // sum quads
      ssum += __shfl_xor(ssum, 32);
      if (l < 16) {
        int g = m_half * 2 + gl;
        pl[g * 128 + n0 + n * 16 + lane15] = ssum * (1.f / 64.f);
      }
    }
  }
  __syncthreads();

  // ---- fused routing epilogue: wave w handles sample (n_s + w) ----
  const float* plw = pl + w * 128;
  int e  = l >> 3;                                 // expert 0..7
  int c8 = l & 7;
  float part = 0.f;
  #pragma unroll
  for (int m = 0; m < 16; ++m) {
    int co = c8 + 8 * m;
    part += plw[co] * fc_w[co * 8 + e];            // LDS broadcast + cached fc_w
  }
  part += __shfl_xor(part, 1);
  part += __shfl_xor(part, 2);
  part += __shfl_xor(part, 4);

  float lg[8];
  #pragma unroll
  for (int j = 0; j < 8; ++j) lg[j] = __shfl(part, j * 8) + fc_b[j];

  // softmax (all lanes redundantly)
  float mx = lg[0];
  #pragma unroll
  for (int j = 1; j < 8; ++j) mx = fmaxf(mx, lg[j]);
  float wgt[8]; float sum = 0.f;
  #pragma unroll
  for (int j = 0; j < 8; ++j) { wgt[j] = expf(lg[j] - mx); sum += wgt[j]; }
  float inv = 1.f / sum;
  #pragma unroll
  for (int j = 0; j < 8; ++j) wgt[j] *= inv;

  // sort descending — Batcher odd-even, 19 comparators
  float sw[8];
  #pragma unroll
  for (int j = 0; j < 8; ++j) sw[j] = wgt[j];
  #define CSD(i, j) { float hi_ = fmaxf(sw[i], sw[j]); float lo_ = fminf(sw[i], sw[j]); sw[i] = hi_; sw[j] = lo_; }
  CSD(0,1) CSD(2,3) CSD(4,5) CSD(6,7)
  CSD(0,2) CSD(1,3) CSD(4,6) CSD(5,7)
  CSD(1,2) CSD(5,6)
  CSD(0,4) CSD(1,5) CSD(2,6) CSD(3,7)
  CSD(2,4) CSD(3,5)
  CSD(1,2) CSD(3,4) CSD(5,6)
  #undef CSD

  float s1 = 0.f;
  #pragma unroll
  for (int j = 0; j < 8; ++j) s1 += wgt[j];
  float mean = s1 * 0.125f;
  float var = 0.f;
  #pragma unroll
  for (int j = 0; j < 8; ++j) { float d = wgt[j] - mean; var += d * d; }
  float stdv = sqrtf(var * (1.f / 7.f));          // ddof=1
  float ent = 0.f;
  #pragma unroll
  for (int j = 0; j < 8; ++j) ent -= wgt[j] * logf(wgt[j] + 1e-18f);

  float maxc  = 1.f - sw[0];
  float entc  = 1.f - ent * 0.48089834696298783f; // 1/log(8)
  float mrest = (sw[1] + sw[2] + sw[3] + sw[4]) * 0.25f;
  float gap   = (sw[0] - mrest) / (sw[0] + 1e-8f);
  gap = fminf(fmaxf(gap, 0.f), 1.f);
  float af = p_wmax[0] * maxc + p_went[0] * entc + p_wgap[0] * gap;
  float th = p_thr[0] * (0.5f + af);
  float mn  = fmaxf(0.05f, mean - 0.5f * stdv);
  float mxt = fminf(0.7f, sw[0] - 0.1f * stdv);
  th = fminf(fmaxf(th, mn), mxt);                 // jnp.clip order: lower then upper
  th = fminf(th, sw[1] * 0.9f);                   // kth = sw[MIN_EXPERTS_ACTIVE-1]

  int epoch = p_epoch[0];
  float outv[8];
  if (epoch < 20) {
    #pragma unroll
    for (int j = 0; j < 8; ++j) outv[j] = 0.125f;
  } else {
    float tau = (epoch <= 25) ? fmaxf(0.1f, 1.0f - (float)(epoch - 20) * 0.18f) : 0.1f;
    // forward: hard + stopgrad(soft-hard) == soft exactly
    float ssum = 0.f;
    #pragma unroll
    for (int j = 0; j < 8; ++j) {
      float sj = 1.f / (1.f + expf(-(wgt[j] - th) / tau));
      outv[j] = sj; ssum += sj;
    }
    float invs = 1.f / fmaxf(ssum, 1e-8f);
    #pragma unroll
    for (int j = 0; j < 8; ++j) outv[j] *= invs;
  }

  if (l < 8) {
    float mv = outv[0];
    #pragma unroll
    for (int j = 1; j < 8; ++j) mv = (l == j) ? outv[j] : mv;
    out[(n_s + w) * 8 + l] = mv;
  }
}

extern "C" void kernel_launch(void* const* d_in, const int* in_sizes, int n_in,
                              void* d_out, int out_size, void* d_ws, size_t ws_size,
                              hipStream_t stream) {
  const float* patch  = (const float*)d_in[0];
  const float* conv_w = (const float*)d_in[1];
  const float* conv_b = (const float*)d_in[2];
  const float* fc_w   = (const float*)d_in[3];
  const float* fc_b   = (const float*)d_in[4];
  const float* wmax   = (const float*)d_in[5];
  const float* went   = (const float*)d_in[6];
  const float* wgap   = (const float*)d_in[7];
  const float* thr    = (const float*)d_in[8];
  const int*   epoch  = (const int*)d_in[10];
  float* outp = (float*)d_out;
  _Float16* Bw = (_Float16*)d_ws;                 // needs 128*672*2 = 172,032 B of ws

  int N = in_sizes[0] / 4352;                     // 16384 samples
  prep_weights<<<336, 256, 0, stream>>>(conv_w, Bw);
  router_main<<<N / 4, 256, 0, stream>>>(patch, conv_b, Bw, fc_w, fc_b,
                                         wmax, went, wgap, thr, epoch, outp);
}

// Round 2
// 496.161 us; speedup vs baseline: 1.0444x; 1.0444x over previous
//
#include <hip/hip_runtime.h>

// Router_26817775796684 — MI355X/gfx950, round 2.
// conv3x3(SAME)+relu+meanpool+fc+softmax+adaptive-threshold+sigmoid-renorm, fused.
//
// Round-2 structure (changes vs round 1 marked *):
//   prep_weights: conv_w fp32 -> fp16 Bw[co][k=672], k = s*72+ci (zero pads).
//   router_main:  WG = 4 samples, 4 waves, wave tile 128(M)x64(N), 16x16x32 f16 MFMA.
//   * A staged as zero-padded 10x10 spatial grid [100 rows][72 ci] f16 (144 B rows):
//     shift remap becomes ONE affine byte-offset per chunk — no bounds checks/cndmask.
//   * B fragments loaded per-lane from global (L2-resident, 172 KB) into registers,
//     register-double-buffered: no B LDS staging, no K-loop barriers at all.
//   * Tail chunk c=20 peeled (kb 81..83 hit exact-zero B columns; A offset clamped).

typedef _Float16 half8 __attribute__((ext_vector_type(8)));
typedef float    floatx4 __attribute__((ext_vector_type(4)));

#define A_SAMPLE  14400              // 100 rows * 144 B
#define LDS_P_OFF 57600              // pooled[4][128] fp32 after 4 A samples
#define LDS_TOTAL 59648

__global__ void prep_weights(const float* __restrict__ cw, _Float16* __restrict__ Bw) {
  int i = blockIdx.x * 256 + threadIdx.x;   // 0 .. 128*672-1
  int co = i / 672;
  int k  = i - co * 672;
  int s  = k / 72;                          // shift index (9 real, 9 = tail pad)
  int ci = k - s * 72;
  float v = 0.f;
  if (s < 9 && ci < 68) {
    int ky = s / 3, kx = s - 3 * ky;
    v = cw[((co * 68 + ci) * 3 + ky) * 3 + kx];
  }
  Bw[i] = (_Float16)v;                      // pads are EXACT zeros (never NaN)
}

__global__ __launch_bounds__(256, 2) void router_main(
    const float* __restrict__ patch,
    const float* __restrict__ conv_b,
    const _Float16* __restrict__ Bw,
    const float* __restrict__ fc_w,
    const float* __restrict__ fc_b,
    const float* __restrict__ p_wmax,
    const float* __restrict__ p_went,
    const float* __restrict__ p_wgap,
    const float* __restrict__ p_thr,
    const int* __restrict__ p_epoch,
    float* __restrict__ out)
{
  __shared__ __align__(16) unsigned char lds[LDS_TOTAL];
  const int tid    = threadIdx.x;
  const int l      = tid & 63;
  const int w      = tid >> 6;      // wave 0..3
  const int lane15 = l & 15;
  const int quad   = l >> 4;
  const int m_half = w >> 1;        // which sample-pair this wave computes
  const int n0     = (w & 1) * 64;  // N 64-half
  const int n_s    = blockIdx.x * 4;

  // ---- zero-fill own sample's padded A region (border rows become zeros) ----
  {
    unsigned char* abase = lds + w * A_SAMPLE;
    float4 z4 = make_float4(0.f, 0.f, 0.f, 0.f);
    #pragma unroll
    for (int j = 0; j < 15; ++j) {
      int idx = j * 64 + l;                 // 900 b128 slots per sample
      if (idx < 900) *(float4*)(abase + idx * 16) = z4;
    }
  }
  // ---- stage interior: lane l = position p=(y,x) -> padded row (y+1)*10+(x+1) ----
  // (DS instructions from one wave are processed in order: fill-then-write is safe.)
  {
    const float* psrc = patch + (size_t)(n_s + w) * 4352 + l;   // [ci][p] layout
    int y = l >> 3, x = l & 7;
    unsigned char* arow = lds + w * A_SAMPLE + ((y + 1) * 10 + (x + 1)) * 144;
    #pragma unroll
    for (int b = 0; b < 9; ++b) {           // 9 ci-blocks of 8 (68 real + 4 zero pad)
      half8 h;
      #pragma unroll
      for (int j = 0; j < 8; ++j) {
        int ci = b * 8 + j;
        float v = (ci < 68) ? psrc[ci * 64] : 0.f;   // 256 B/wave coalesced
        h[j] = (_Float16)v;
      }
      *(half8*)(arow + b * 16) = h;
    }
  }
  __syncthreads();

  // ---- loop-invariant A fragment base offsets (this wave's 8 M-tiles) ----
  int apos[8];
  #pragma unroll
  for (int t = 0; t < 8; ++t) {
    int p  = (t & 3) * 16 + lane15;                       // position within sample
    int pp = ((p >> 3) + 1) * 10 + (p & 7) + 1;           // padded row
    apos[t] = (m_half * 2 + (t >> 2)) * A_SAMPLE + pp * 144;
  }

  // ---- B gather pointers (per-lane; 172 KB table is L2-resident) ----
  const _Float16* bptr[4];
  #pragma unroll
  for (int n = 0; n < 4; ++n)
    bptr[n] = Bw + (size_t)(n0 + n * 16 + lane15) * 672 + quad * 8;

  floatx4 acc[8][4];
  floatx4 zacc = {0.f, 0.f, 0.f, 0.f};
  #pragma unroll
  for (int t = 0; t < 8; ++t)
    #pragma unroll
    for (int n = 0; n < 4; ++n) acc[t][n] = zacc;

  // preload B chunk 0 into registers
  half8 bcur[4];
  #pragma unroll
  for (int n = 0; n < 4; ++n) bcur[n] = *(const half8*)(bptr[n]);

  // ---- barrier-free K loop: 20 full chunks (kb = 4c+quad <= 79, all valid) ----
  #pragma unroll 4
  for (int c = 0; c < 20; ++c) {
    half8 bnext[4];
    #pragma unroll
    for (int n = 0; n < 4; ++n)
      bnext[n] = *(const half8*)(bptr[n] + (c + 1) * 32);  // const offset folds

    int kb  = c * 4 + quad;
    int s   = (kb * 57) >> 9;           // kb/9, exact for 0..83
    int rem = kb - s * 9;
    int dy  = (s * 11) >> 5;            // s/3
    int dx  = s - 3 * dy;
    int roff = (dy * 10 + dx - 11) * 144 + rem * 16;       // affine shift offset

    half8 afr[8];
    #pragma unroll
    for (int t = 0; t < 8; ++t)
      afr[t] = *(const half8*)(lds + apos[t] + roff);

    #pragma unroll
    for (int t = 0; t < 8; ++t)
      #pragma unroll
      for (int n = 0; n < 4; ++n)
        acc[t][n] = __builtin_amdgcn_mfma_f32_16x16x32_f16(afr[t], bcur[n], acc[t][n], 0, 0, 0);

    #pragma unroll
    for (int n = 0; n < 4; ++n) bcur[n] = bnext[n];
  }

  // ---- peeled tail chunk c=20: kb=80 (quad 0) real; kb 81..83 are zero B columns,
  //      so A contents are irrelevant — clamp offset in-bounds (finite data). ----
  {
    int roff = (quad == 0) ? 1712 : 0;  // kb=80: s=8,rem=8 -> (20+2-11)*144+128
    half8 afr[8];
    #pragma unroll
    for (int t = 0; t < 8; ++t)
      afr[t] = *(const half8*)(lds + apos[t] + roff);
    #pragma unroll
    for (int t = 0; t < 8; ++t)
      #pragma unroll
      for (int n = 0; n < 4; ++n)
        acc[t][n] = __builtin_amdgcn_mfma_f32_16x16x32_f16(afr[t], bcur[n], acc[t][n], 0, 0, 0);
  }

  // ---- bias + relu + mean-pool (C layout: row = quad*4+reg, col = lane15) ----
  float bcoef[4];
  #pragma unroll
  for (int n = 0; n < 4; ++n) bcoef[n] = conv_b[n0 + n * 16 + lane15];

  float* pl = (float*)(lds + LDS_P_OFF);          // pooled[4][128]
  #pragma unroll
  for (int gl = 0; gl < 2; ++gl) {
    #pragma unroll
    for (int n = 0; n < 4; ++n) {
      float ssum = 0.f;
      #pragma unroll
      for (int tt = 0; tt < 4; ++tt) {
        int t = gl * 4 + tt;
        #pragma unroll
        for (int r = 0; r < 4; ++r)
          ssum += fmaxf(acc[t][n][r] + bcoef[n], 0.f);
      }
      ssum += __shfl_xor(ssum, 16);               // sum the 4 quad partials
      ssum += __shfl_xor(ssum, 32);
      if (l < 16) {
        int g = m_half * 2 + gl;
        pl[g * 128 + n0 + n * 16 + lane15] = ssum * (1.f / 64.f);
      }
    }
  }
  __syncthreads();

  // ---- fused routing epilogue: wave w handles sample (n_s + w) ----
  const float* plw = pl + w * 128;
  int e  = l >> 3;                                 // expert 0..7
  int c8 = l & 7;
  float part = 0.f;
  #pragma unroll
  for (int m = 0; m < 16; ++m) {
    int co = c8 + 8 * m;
    part += plw[co] * fc_w[co * 8 + e];
  }
  part += __shfl_xor(part, 1);
  part += __shfl_xor(part, 2);
  part += __shfl_xor(part, 4);

  float lg[8];
  #pragma unroll
  for (int j = 0; j < 8; ++j) lg[j] = __shfl(part, j * 8) + fc_b[j];

  float mx = lg[0];
  #pragma unroll
  for (int j = 1; j < 8; ++j) mx = fmaxf(mx, lg[j]);
  float wgt[8]; float sum = 0.f;
  #pragma unroll
  for (int j = 0; j < 8; ++j) { wgt[j] = expf(lg[j] - mx); sum += wgt[j]; }
  float inv = 1.f / sum;
  #pragma unroll
  for (int j = 0; j < 8; ++j) wgt[j] *= inv;

  // sort descending — Batcher odd-even, 19 comparators
  float sw[8];
  #pragma unroll
  for (int j = 0; j < 8; ++j) sw[j] = wgt[j];
  #define CSD(i, j) { float hi_ = fmaxf(sw[i], sw[j]); float lo_ = fminf(sw[i], sw[j]); sw[i] = hi_; sw[j] = lo_; }
  CSD(0,1) CSD(2,3) CSD(4,5) CSD(6,7)
  CSD(0,2) CSD(1,3) CSD(4,6) CSD(5,7)
  CSD(1,2) CSD(5,6)
  CSD(0,4) CSD(1,5) CSD(2,6) CSD(3,7)
  CSD(2,4) CSD(3,5)
  CSD(1,2) CSD(3,4) CSD(5,6)
  #undef CSD

  float s1 = 0.f;
  #pragma unroll
  for (int j = 0; j < 8; ++j) s1 += wgt[j];
  float mean = s1 * 0.125f;
  float var = 0.f;
  #pragma unroll
  for (int j = 0; j < 8; ++j) { float d = wgt[j] - mean; var += d * d; }
  float stdv = sqrtf(var * (1.f / 7.f));          // ddof=1
  float ent = 0.f;
  #pragma unroll
  for (int j = 0; j < 8; ++j) ent -= wgt[j] * logf(wgt[j] + 1e-18f);

  float maxc  = 1.f - sw[0];
  float entc  = 1.f - ent * 0.48089834696298783f; // 1/log(8)
  float mrest = (sw[1] + sw[2] + sw[3] + sw[4]) * 0.25f;
  float gap   = (sw[0] - mrest) / (sw[0] + 1e-8f);
  gap = fminf(fmaxf(gap, 0.f), 1.f);
  float af = p_wmax[0] * maxc + p_went[0] * entc + p_wgap[0] * gap;
  float th = p_thr[0] * (0.5f + af);
  float mn  = fmaxf(0.05f, mean - 0.5f * stdv);
  float mxt = fminf(0.7f, sw[0] - 0.1f * stdv);
  th = fminf(fmaxf(th, mn), mxt);                 // jnp.clip: lower then upper
  th = fminf(th, sw[1] * 0.9f);                   // kth = sw[MIN_EXPERTS_ACTIVE-1]

  int epoch = p_epoch[0];
  float outv[8];
  if (epoch < 20) {
    #pragma unroll
    for (int j = 0; j < 8; ++j) outv[j] = 0.125f;
  } else {
    float tau = (epoch <= 25) ? fmaxf(0.1f, 1.0f - (float)(epoch - 20) * 0.18f) : 0.1f;
    // forward value of hard + stopgrad(soft-hard) == soft exactly
    float ssum = 0.f;
    #pragma unroll
    for (int j = 0; j < 8; ++j) {
      float sj = 1.f / (1.f + expf(-(wgt[j] - th) / tau));
      outv[j] = sj; ssum += sj;
    }
    float invs = 1.f / fmaxf(ssum, 1e-8f);
    #pragma unroll
    for (int j = 0; j < 8; ++j) outv[j] *= invs;
  }

  if (l < 8) {
    float mv = outv[0];
    #pragma unroll
    for (int j = 1; j < 8; ++j) mv = (l == j) ? outv[j] : mv;
    out[(n_s + w) * 8 + l] = mv;
  }
}

extern "C" void kernel_launch(void* const* d_in, const int* in_sizes, int n_in,
                              void* d_out, int out_size, void* d_ws, size_t ws_size,
                              hipStream_t stream) {
  const float* patch  = (const float*)d_in[0];
  const float* conv_w = (const float*)d_in[1];
  const float* conv_b = (const float*)d_in[2];
  const float* fc_w   = (const float*)d_in[3];
  const float* fc_b   = (const float*)d_in[4];
  const float* wmax   = (const float*)d_in[5];
  const float* went   = (const float*)d_in[6];
  const float* wgap   = (const float*)d_in[7];
  const float* thr    = (const float*)d_in[8];
  const int*   epoch  = (const int*)d_in[10];
  float* outp = (float*)d_out;
  _Float16* Bw = (_Float16*)d_ws;                 // 128*672*2 = 172,032 B of ws

  int N = in_sizes[0] / 4352;                     // 16384 samples
  prep_weights<<<336, 256, 0, stream>>>(conv_w, Bw);
  router_main<<<N / 4, 256, 0, stream>>>(patch, conv_b, Bw, fc_w, fc_b,
                                         wmax, went, wgap, thr, epoch, outp);
}